// Round 18
// baseline (175.369 us; speedup 1.0000x reference)
//
#include <hip/hip_runtime.h>

// Fused SNN forward for MI355X (gfx950) — round 18 (= r17 + combine fix).
// r17 failed because the split-combine did `if (tid < 320)` in a 256-thread
// block: scur2[256..319] (image 1, t >= 9.6) stayed poisoned -> absmax 3.0.
// Fix: grid-stride combine (2 iters/thread). Design unchanged:
//   2 images/block processed CONCURRENTLY; one bw weight load feeds two
//   MFMAs (acc0/acc1); u8 counts (r15-exact); scC aliases sAb after a
//   barrier; 4-way exact bf16 weight split; pairwise combine; 20-thread
//   LIF-2 tail.

typedef float v2f __attribute__((ext_vector_type(2)));
typedef float f32x4 __attribute__((ext_vector_type(4)));
typedef short s16x8 __attribute__((ext_vector_type(8)));

#if __has_builtin(__builtin_elementwise_fma)
#define VFMA(a, b, c) __builtin_elementwise_fma((a), (b), (c))
#else
#define VFMA(a, b, c) ((a) * (b) + (c))
#endif

#define NU 6            // units per thread per image
#define KS 43           // K-blocks of 32: 43*32 = 1376 >= 1352
#define SPLITS 4        // exact bf16 decomposition of fp32 weights (== waves)
#define IMG 2           // images per block
#define SA_BYTES (KS * 544)   // 23392 B per image

__device__ __forceinline__ unsigned short bf16_rne(float f) {
    unsigned u = __float_as_uint(f);
    return (unsigned short)((u + 0x7FFFu + ((u >> 16) & 1u)) >> 16);
}
__device__ __forceinline__ float bf16_back(unsigned short h) {
    return __uint_as_float(((unsigned)h) << 16);
}

// pack two small-int floats into one bf16-pair word (exact): lo | hi<<16
__device__ __forceinline__ unsigned bf16pair(float flo, float fhi) {
#if __has_builtin(__builtin_amdgcn_perm)
    return __builtin_amdgcn_perm(__float_as_uint(fhi), __float_as_uint(flo),
                                 0x07060302u);
#else
    return (__float_as_uint(fhi) & 0xFFFF0000u) | (__float_as_uint(flo) >> 16);
#endif
}

// expand 8 u8 counts (uint2) -> MFMA A-fragment of 8 exact bf16
__device__ __forceinline__ s16x8 unpack8(uint2 av) {
    const float f0 = (float)( av.x        & 0xFF);
    const float f1 = (float)((av.x >>  8) & 0xFF);
    const float f2 = (float)((av.x >> 16) & 0xFF);
    const float f3 = (float)( av.x >> 24);
    const float f4 = (float)( av.y        & 0xFF);
    const float f5 = (float)((av.y >>  8) & 0xFF);
    const float f6 = (float)((av.y >> 16) & 0xFF);
    const float f7 = (float)( av.y >> 24);
    union { uint4 u; s16x8 v; } au;
    au.u.x = bf16pair(f0, f1);
    au.u.y = bf16pair(f2, f3);
    au.u.z = bf16pair(f4, f5);
    au.u.w = bf16pair(f6, f7);
    return au.v;
}

// ---- pre-kernel: build B fragments (4-way exact bf16 split of 0.25*fc_w)
__global__ void build_bfrag_kernel(const float* __restrict__ fc_w,
                                   s16x8* __restrict__ wsfrag) {
    const int blk = blockIdx.x;          // p*KS + ks
    const int p   = blk / KS;
    const int ks  = blk - p * KS;
    const int l   = threadIdx.x;         // 0..63
    s16x8 frag;
    #pragma unroll
    for (int jj = 0; jj < 8; ++jj) {
        const int k = ks * 32 + (l >> 4) * 8 + jj;
        const int n = l & 15;
        float r = (k < 1352 && n < 10) ? 0.25f * fc_w[n * 1352 + k] : 0.0f;
        unsigned short b = 0;
        for (int q = 0; q <= p; ++q) {   // p-th split term
            b = bf16_rne(r);
            r -= bf16_back(b);
        }
        frag[jj] = (short)b;
    }
    wsfrag[blk * 64 + l] = frag;
}

__global__ __launch_bounds__(256, 3) void snn_fused_kernel(
    const float* __restrict__ x,        // [4096, 1, 28, 28]
    const float* __restrict__ conv_w,   // [8, 1, 3, 3]
    const s16x8* __restrict__ wsfrag,   // [SPLITS*KS*64] B fragments
    float* __restrict__ out)            // [4096, 10]
{
    const int b0   = blockIdx.x * IMG;
    const int tid  = threadIdx.x;
    const int lane = tid & 63;
    const int wid  = tid >> 6;          // 0..3

    // u8 counts, A-fragment order per image:
    // byte(u,t) = (u>>5)*544 + ((u&31)>>3)*136 + t*8 + (u&7)  [+ img*SA_BYTES]
    __shared__ __align__(16) unsigned char sAb[IMG * SA_BYTES];  // 45.7 KB
    __shared__ float scur2[IMG * 160];        // [img][t*10+o]
    __shared__ float scw[72];                 // conv weights
    float* const scC = reinterpret_cast<float*>(sAb);  // aliased AFTER barrier

    if (tid < 72) scw[tid] = conv_w[tid];

    // ---- per-thread unit geometry (shared by both images) ----
    int xbase[NU], kbase[NU], sbase[NU];
    bool uvalid[NU];
    #pragma unroll
    for (int i = 0; i < NU; ++i) {
        const int u      = tid + 256 * i;
        const bool valid = (u < 1352);
        const int uu  = valid ? u : 0;
        const int k   = uu / 169;           // channel
        const int rem = uu - k * 169;
        const int pr  = rem / 13;           // pool row
        const int pc  = rem - pr * 13;      // pool col
        xbase[i]  = 56 * pr + 2 * pc;
        kbase[i]  = 9 * k;
        uvalid[i] = valid;
        const int uo = u & 31;              // raw u: pad rows get own slots
        sbase[i] = (u >> 5) * 544 + (uo >> 3) * 136 + (uo & 7);
    }
    __syncthreads();                        // scw ready

    // ---- conv for both images straight from global (L2/L3-resident) ----
    v2f cur2[IMG][NU][2];   // conv out
    v2f mem2[IMG][NU][2];   // LIF-1 membranes
    #pragma unroll
    for (int img = 0; img < IMG; ++img) {
        const float* xb = x + (size_t)(b0 + img) * 784;
        #pragma unroll
        for (int i = 0; i < NU; ++i) {
            float cw[9];
            #pragma unroll
            for (int qq = 0; qq < 9; ++qq) cw[qq] = scw[kbase[i] + qq];

            float xr[4][4];
            #pragma unroll
            for (int r = 0; r < 4; ++r) {
                const float2* rp = reinterpret_cast<const float2*>(xb + xbase[i] + 28 * r);
                const float2 a = rp[0], c2 = rp[1];
                xr[r][0] = a.x; xr[r][1] = a.y; xr[r][2] = c2.x; xr[r][3] = c2.y;
            }

            float cell[2][2];
            #pragma unroll
            for (int dr = 0; dr < 2; ++dr)
                #pragma unroll
                for (int dc = 0; dc < 2; ++dc) {
                    float acc = 0.0f;
                    #pragma unroll
                    for (int ki = 0; ki < 3; ++ki)
                        #pragma unroll
                        for (int kj = 0; kj < 3; ++kj)
                            acc += xr[dr + ki][dc + kj] * cw[ki * 3 + kj];
                    cell[dr][dc] = uvalid[i] ? acc : 0.0f;
                }
            cur2[img][i][0] = (v2f){cell[0][0], cell[0][1]};
            cur2[img][i][1] = (v2f){cell[1][0], cell[1][1]};
            mem2[img][i][0] = (v2f){0.0f, 0.0f};
            mem2[img][i][1] = (v2f){0.0f, 0.0f};
        }
    }

    const v2f half2 = (v2f){0.5f, 0.5f};

    // ---- phase 1: 16 timesteps of pure LIF (both images); u8 -> sAb ----
    #pragma unroll
    for (int t = 0; t < 16; ++t) {
        #pragma unroll
        for (int img = 0; img < IMG; ++img) {
            #pragma unroll
            for (int i = 0; i < NU; ++i) {
                v2f m01 = VFMA(half2, mem2[img][i][0], cur2[img][i][0]);
                v2f m23 = VFMA(half2, mem2[img][i][1], cur2[img][i][1]);
                v2f sp01, sp23;
                sp01.x = m01.x > 1.0f ? 1.0f : 0.0f;   // spike iff m > THR
                sp01.y = m01.y > 1.0f ? 1.0f : 0.0f;
                sp23.x = m23.x > 1.0f ? 1.0f : 0.0f;
                sp23.y = m23.y > 1.0f ? 1.0f : 0.0f;
                mem2[img][i][0] = m01 - sp01;          // subtract-reset
                mem2[img][i][1] = m23 - sp23;
                v2f s = sp01 + sp23;
                const float c = s.x + s.y;             // 0..4 exact
                if (i < 5 || tid < 96)                 // u < 1376 only
                    sAb[img * SA_BYTES + sbase[i] + t * 8] =
                        (unsigned char)(unsigned)c;
            }
        }
    }
    __syncthreads();                                   // counts complete

    // ---- phase 2: wave p = split p; one bw load feeds BOTH images ----
    f32x4 acc0 = (f32x4){0.f, 0.f, 0.f, 0.f};
    f32x4 acc1 = (f32x4){0.f, 0.f, 0.f, 0.f};
    {
        const int p = wid;
        const int arow = (lane >> 4) * 136 + (lane & 15) * 8;
        #pragma unroll 2
        for (int ks = 0; ks < KS; ++ks) {
            const uint2 a0 = *reinterpret_cast<const uint2*>(&sAb[ks * 544 + arow]);
            const uint2 a1 = *reinterpret_cast<const uint2*>(&sAb[SA_BYTES + ks * 544 + arow]);
            const s16x8 bw = wsfrag[(p * KS + ks) * 64 + lane];
            acc0 = __builtin_amdgcn_mfma_f32_16x16x32_bf16(unpack8(a0), bw, acc0, 0, 0, 0);
            acc1 = __builtin_amdgcn_mfma_f32_16x16x32_bf16(unpack8(a1), bw, acc1, 0, 0, 0);
        }
    }
    __syncthreads();                 // ALL sAb reads done -> safe to alias scC

    // store partials: scC[w*320 + img*160 + t*10 + o]
    {
        const int o = lane & 15;
        if (o < 10) {
            #pragma unroll
            for (int r = 0; r < 4; ++r) {
                const int t = (lane >> 4) * 4 + r;     // verified C layout
                scC[wid * 320 +       t * 10 + o] = acc0[r];
                scC[wid * 320 + 160 + t * 10 + o] = acc1[r];
            }
        }
    }
    __syncthreads();                                   // partials ready

    // ---- combine splits (pairwise, same order as r13/r14) ----
    // FIX (r17 bug): 320 elements, 256 threads -> grid-stride, 2 iters.
    for (int idx = tid; idx < IMG * 160; idx += 256) {
        scur2[idx] = (scC[idx] + scC[320 + idx]) + (scC[640 + idx] + scC[960 + idx]);
    }
    __syncthreads();                                   // scur2 ready

    // ---- LIF-2 scan: 20 threads (2 images x 10 outputs) ----
    if (tid < 20) {
        const int img = tid / 10;
        const int o   = tid - img * 10;
        float m2 = 0.0f, cnt = 0.0f;
        #pragma unroll
        for (int t = 0; t < 16; ++t) {
            m2 = __builtin_fmaf(0.5f, m2, scur2[img * 160 + t * 10 + o]);
            float ms = m2 - 1.0f;
            bool  sp = ms > 0.0f;
            m2  = sp ? ms : m2;
            cnt += sp ? 1.0f : 0.0f;
        }
        out[(size_t)(b0 + img) * 10 + o] = cnt;
    }
}

extern "C" void kernel_launch(void* const* d_in, const int* in_sizes, int n_in,
                              void* d_out, int out_size, void* d_ws, size_t ws_size,
                              hipStream_t stream) {
    const float* x      = (const float*)d_in[0];  // 4096*784
    const float* conv_w = (const float*)d_in[1];  // 72
    const float* fc_w   = (const float*)d_in[2];  // 13520
    float* out          = (float*)d_out;          // 40960
    s16x8* wsfrag       = (s16x8*)d_ws;           // needs 176128 B

    build_bfrag_kernel<<<SPLITS * KS, 64, 0, stream>>>(fc_w, wsfrag);

    const int B = in_sizes[0] / 784;              // 4096
    snn_fused_kernel<<<B / IMG, 256, 0, stream>>>(x, conv_w, wsfrag, out);
}

// Round 19
// 149.019 us; speedup vs baseline: 1.1768x; 1.1768x over previous
//
#include <hip/hip_runtime.h>

// Fused SNN forward for MI355X (gfx950) — round 19 (= r18 + register headroom).
// r18's 191us regression was pure scratch-spill (WRITE 320MB, FETCH 169MB,
// VGPR_Count=84 vs ~125 live floats): launch_bounds(256,3)'s ~170-reg cap
// triggered the r4 allocator pathology (squeeze + spill). Fix: (256,2) ->
// 256-VGPR budget >> live set; 2 blocks/CU (~25% occ ~= r14's 27.6%, which
// r15 showed is not the limiter). Everything else identical to r18:
// 2 concurrent images/block, shared bw loads (1 load -> 2 MFMAs), u8 counts,
// scC aliases sAb after barrier, 4-way exact bf16 split, grid-stride combine.

typedef float v2f __attribute__((ext_vector_type(2)));
typedef float f32x4 __attribute__((ext_vector_type(4)));
typedef short s16x8 __attribute__((ext_vector_type(8)));

#if __has_builtin(__builtin_elementwise_fma)
#define VFMA(a, b, c) __builtin_elementwise_fma((a), (b), (c))
#else
#define VFMA(a, b, c) ((a) * (b) + (c))
#endif

#define NU 6            // units per thread per image
#define KS 43           // K-blocks of 32: 43*32 = 1376 >= 1352
#define SPLITS 4        // exact bf16 decomposition of fp32 weights (== waves)
#define IMG 2           // images per block
#define SA_BYTES (KS * 544)   // 23392 B per image

__device__ __forceinline__ unsigned short bf16_rne(float f) {
    unsigned u = __float_as_uint(f);
    return (unsigned short)((u + 0x7FFFu + ((u >> 16) & 1u)) >> 16);
}
__device__ __forceinline__ float bf16_back(unsigned short h) {
    return __uint_as_float(((unsigned)h) << 16);
}

// pack two small-int floats into one bf16-pair word (exact): lo | hi<<16
__device__ __forceinline__ unsigned bf16pair(float flo, float fhi) {
#if __has_builtin(__builtin_amdgcn_perm)
    return __builtin_amdgcn_perm(__float_as_uint(fhi), __float_as_uint(flo),
                                 0x07060302u);
#else
    return (__float_as_uint(fhi) & 0xFFFF0000u) | (__float_as_uint(flo) >> 16);
#endif
}

// expand 8 u8 counts (uint2) -> MFMA A-fragment of 8 exact bf16
__device__ __forceinline__ s16x8 unpack8(uint2 av) {
    const float f0 = (float)( av.x        & 0xFF);
    const float f1 = (float)((av.x >>  8) & 0xFF);
    const float f2 = (float)((av.x >> 16) & 0xFF);
    const float f3 = (float)( av.x >> 24);
    const float f4 = (float)( av.y        & 0xFF);
    const float f5 = (float)((av.y >>  8) & 0xFF);
    const float f6 = (float)((av.y >> 16) & 0xFF);
    const float f7 = (float)( av.y >> 24);
    union { uint4 u; s16x8 v; } au;
    au.u.x = bf16pair(f0, f1);
    au.u.y = bf16pair(f2, f3);
    au.u.z = bf16pair(f4, f5);
    au.u.w = bf16pair(f6, f7);
    return au.v;
}

// ---- pre-kernel: build B fragments (4-way exact bf16 split of 0.25*fc_w)
__global__ void build_bfrag_kernel(const float* __restrict__ fc_w,
                                   s16x8* __restrict__ wsfrag) {
    const int blk = blockIdx.x;          // p*KS + ks
    const int p   = blk / KS;
    const int ks  = blk - p * KS;
    const int l   = threadIdx.x;         // 0..63
    s16x8 frag;
    #pragma unroll
    for (int jj = 0; jj < 8; ++jj) {
        const int k = ks * 32 + (l >> 4) * 8 + jj;
        const int n = l & 15;
        float r = (k < 1352 && n < 10) ? 0.25f * fc_w[n * 1352 + k] : 0.0f;
        unsigned short b = 0;
        for (int q = 0; q <= p; ++q) {   // p-th split term
            b = bf16_rne(r);
            r -= bf16_back(b);
        }
        frag[jj] = (short)b;
    }
    wsfrag[blk * 64 + l] = frag;
}

__global__ __launch_bounds__(256, 2) void snn_fused_kernel(
    const float* __restrict__ x,        // [4096, 1, 28, 28]
    const float* __restrict__ conv_w,   // [8, 1, 3, 3]
    const s16x8* __restrict__ wsfrag,   // [SPLITS*KS*64] B fragments
    float* __restrict__ out)            // [4096, 10]
{
    const int b0   = blockIdx.x * IMG;
    const int tid  = threadIdx.x;
    const int lane = tid & 63;
    const int wid  = tid >> 6;          // 0..3

    // u8 counts, A-fragment order per image:
    // byte(u,t) = (u>>5)*544 + ((u&31)>>3)*136 + t*8 + (u&7)  [+ img*SA_BYTES]
    __shared__ __align__(16) unsigned char sAb[IMG * SA_BYTES];  // 45.7 KB
    __shared__ float scur2[IMG * 160];        // [img][t*10+o]
    __shared__ float scw[72];                 // conv weights
    float* const scC = reinterpret_cast<float*>(sAb);  // aliased AFTER barrier

    if (tid < 72) scw[tid] = conv_w[tid];

    // ---- per-thread unit geometry (shared by both images) ----
    int xbase[NU], kbase[NU], sbase[NU];
    bool uvalid[NU];
    #pragma unroll
    for (int i = 0; i < NU; ++i) {
        const int u      = tid + 256 * i;
        const bool valid = (u < 1352);
        const int uu  = valid ? u : 0;
        const int k   = uu / 169;           // channel
        const int rem = uu - k * 169;
        const int pr  = rem / 13;           // pool row
        const int pc  = rem - pr * 13;      // pool col
        xbase[i]  = 56 * pr + 2 * pc;
        kbase[i]  = 9 * k;
        uvalid[i] = valid;
        const int uo = u & 31;              // raw u: pad rows get own slots
        sbase[i] = (u >> 5) * 544 + (uo >> 3) * 136 + (uo & 7);
    }
    __syncthreads();                        // scw ready

    // ---- conv for both images straight from global (L2/L3-resident) ----
    v2f cur2[IMG][NU][2];   // conv out
    v2f mem2[IMG][NU][2];   // LIF-1 membranes
    #pragma unroll
    for (int img = 0; img < IMG; ++img) {
        const float* xb = x + (size_t)(b0 + img) * 784;
        #pragma unroll
        for (int i = 0; i < NU; ++i) {
            float cw[9];
            #pragma unroll
            for (int qq = 0; qq < 9; ++qq) cw[qq] = scw[kbase[i] + qq];

            float xr[4][4];
            #pragma unroll
            for (int r = 0; r < 4; ++r) {
                const float2* rp = reinterpret_cast<const float2*>(xb + xbase[i] + 28 * r);
                const float2 a = rp[0], c2 = rp[1];
                xr[r][0] = a.x; xr[r][1] = a.y; xr[r][2] = c2.x; xr[r][3] = c2.y;
            }

            float cell[2][2];
            #pragma unroll
            for (int dr = 0; dr < 2; ++dr)
                #pragma unroll
                for (int dc = 0; dc < 2; ++dc) {
                    float acc = 0.0f;
                    #pragma unroll
                    for (int ki = 0; ki < 3; ++ki)
                        #pragma unroll
                        for (int kj = 0; kj < 3; ++kj)
                            acc += xr[dr + ki][dc + kj] * cw[ki * 3 + kj];
                    cell[dr][dc] = uvalid[i] ? acc : 0.0f;
                }
            cur2[img][i][0] = (v2f){cell[0][0], cell[0][1]};
            cur2[img][i][1] = (v2f){cell[1][0], cell[1][1]};
            mem2[img][i][0] = (v2f){0.0f, 0.0f};
            mem2[img][i][1] = (v2f){0.0f, 0.0f};
        }
    }

    const v2f half2 = (v2f){0.5f, 0.5f};

    // ---- phase 1: 16 timesteps of pure LIF (both images); u8 -> sAb ----
    #pragma unroll
    for (int t = 0; t < 16; ++t) {
        #pragma unroll
        for (int img = 0; img < IMG; ++img) {
            #pragma unroll
            for (int i = 0; i < NU; ++i) {
                v2f m01 = VFMA(half2, mem2[img][i][0], cur2[img][i][0]);
                v2f m23 = VFMA(half2, mem2[img][i][1], cur2[img][i][1]);
                v2f sp01, sp23;
                sp01.x = m01.x > 1.0f ? 1.0f : 0.0f;   // spike iff m > THR
                sp01.y = m01.y > 1.0f ? 1.0f : 0.0f;
                sp23.x = m23.x > 1.0f ? 1.0f : 0.0f;
                sp23.y = m23.y > 1.0f ? 1.0f : 0.0f;
                mem2[img][i][0] = m01 - sp01;          // subtract-reset
                mem2[img][i][1] = m23 - sp23;
                v2f s = sp01 + sp23;
                const float c = s.x + s.y;             // 0..4 exact
                if (i < 5 || tid < 96)                 // u < 1376 only
                    sAb[img * SA_BYTES + sbase[i] + t * 8] =
                        (unsigned char)(unsigned)c;
            }
        }
    }
    __syncthreads();                                   // counts complete

    // ---- phase 2: wave p = split p; one bw load feeds BOTH images ----
    f32x4 acc0 = (f32x4){0.f, 0.f, 0.f, 0.f};
    f32x4 acc1 = (f32x4){0.f, 0.f, 0.f, 0.f};
    {
        const int p = wid;
        const int arow = (lane >> 4) * 136 + (lane & 15) * 8;
        #pragma unroll 2
        for (int ks = 0; ks < KS; ++ks) {
            const uint2 a0 = *reinterpret_cast<const uint2*>(&sAb[ks * 544 + arow]);
            const uint2 a1 = *reinterpret_cast<const uint2*>(&sAb[SA_BYTES + ks * 544 + arow]);
            const s16x8 bw = wsfrag[(p * KS + ks) * 64 + lane];
            acc0 = __builtin_amdgcn_mfma_f32_16x16x32_bf16(unpack8(a0), bw, acc0, 0, 0, 0);
            acc1 = __builtin_amdgcn_mfma_f32_16x16x32_bf16(unpack8(a1), bw, acc1, 0, 0, 0);
        }
    }
    __syncthreads();                 // ALL sAb reads done -> safe to alias scC

    // store partials: scC[w*320 + img*160 + t*10 + o]
    {
        const int o = lane & 15;
        if (o < 10) {
            #pragma unroll
            for (int r = 0; r < 4; ++r) {
                const int t = (lane >> 4) * 4 + r;     // verified C layout
                scC[wid * 320 +       t * 10 + o] = acc0[r];
                scC[wid * 320 + 160 + t * 10 + o] = acc1[r];
            }
        }
    }
    __syncthreads();                                   // partials ready

    // ---- combine splits (pairwise; grid-stride over 320 elements) ----
    for (int idx = tid; idx < IMG * 160; idx += 256) {
        scur2[idx] = (scC[idx] + scC[320 + idx]) + (scC[640 + idx] + scC[960 + idx]);
    }
    __syncthreads();                                   // scur2 ready

    // ---- LIF-2 scan: 20 threads (2 images x 10 outputs) ----
    if (tid < 20) {
        const int img = tid / 10;
        const int o   = tid - img * 10;
        float m2 = 0.0f, cnt = 0.0f;
        #pragma unroll
        for (int t = 0; t < 16; ++t) {
            m2 = __builtin_fmaf(0.5f, m2, scur2[img * 160 + t * 10 + o]);
            float ms = m2 - 1.0f;
            bool  sp = ms > 0.0f;
            m2  = sp ? ms : m2;
            cnt += sp ? 1.0f : 0.0f;
        }
        out[(size_t)(b0 + img) * 10 + o] = cnt;
    }
}

extern "C" void kernel_launch(void* const* d_in, const int* in_sizes, int n_in,
                              void* d_out, int out_size, void* d_ws, size_t ws_size,
                              hipStream_t stream) {
    const float* x      = (const float*)d_in[0];  // 4096*784
    const float* conv_w = (const float*)d_in[1];  // 72
    const float* fc_w   = (const float*)d_in[2];  // 13520
    float* out          = (float*)d_out;          // 40960
    s16x8* wsfrag       = (s16x8*)d_ws;           // needs 176128 B

    build_bfrag_kernel<<<SPLITS * KS, 64, 0, stream>>>(fc_w, wsfrag);

    const int B = in_sizes[0] / 784;              // 4096
    snn_fused_kernel<<<B / IMG, 256, 0, stream>>>(x, conv_w, wsfrag, out);
}

// Round 20
// 76.355 us; speedup vs baseline: 2.2968x; 1.9517x over previous
//
#include <hip/hip_runtime.h>

// Fused SNN forward for MI355X (gfx950) — round 20: VERBATIM revert to r14,
// the session's measured optimum (76.3us e2e / 78.5us profiled, absmax 0).
// r13 + WAVE-PARALLEL phase 2: wave p computes weight-split p (SPLITS=4 maps
// 1:1 onto the 4 waves). Each wave: 43 x {1 global load + 1 ds_read_b128 +
// 1 MFMA}, loads independent across iters and waves. Partial C per wave ->
// scC; final reduce sums splits pairwise. Probe axes closed by evidence:
// instr-count (r6-r9 null), occupancy (r15 null), DS traffic (r16 regress),
// images/block (r10 serial regress; r17-r19 concurrent = allocator spills).

typedef float v2f __attribute__((ext_vector_type(2)));
typedef float f32x4 __attribute__((ext_vector_type(4)));
typedef short s16x8 __attribute__((ext_vector_type(8)));

#if __has_builtin(__builtin_elementwise_fma)
#define VFMA(a, b, c) __builtin_elementwise_fma((a), (b), (c))
#else
#define VFMA(a, b, c) ((a) * (b) + (c))
#endif

#define NU 6        // units per thread (256*6 = 1536 >= 1376)
#define KS 43       // K-blocks of 32: 43*32 = 1376 >= 1352
#define SPLITS 4    // exact bf16 decomposition of fp32 weights (== waves)

__device__ __forceinline__ unsigned short bf16_rne(float f) {
    unsigned u = __float_as_uint(f);
    return (unsigned short)((u + 0x7FFFu + ((u >> 16) & 1u)) >> 16);
}
__device__ __forceinline__ float bf16_back(unsigned short h) {
    return __uint_as_float(((unsigned)h) << 16);
}

// ---- pre-kernel: build B fragments (4-way exact bf16 split of 0.25*fc_w)
__global__ void build_bfrag_kernel(const float* __restrict__ fc_w,
                                   s16x8* __restrict__ wsfrag) {
    const int blk = blockIdx.x;          // p*KS + ks
    const int p   = blk / KS;
    const int ks  = blk - p * KS;
    const int l   = threadIdx.x;         // 0..63
    s16x8 frag;
    #pragma unroll
    for (int jj = 0; jj < 8; ++jj) {
        const int k = ks * 32 + (l >> 4) * 8 + jj;
        const int n = l & 15;
        float r = (k < 1352 && n < 10) ? 0.25f * fc_w[n * 1352 + k] : 0.0f;
        unsigned short b = 0;
        for (int q = 0; q <= p; ++q) {   // p-th split term
            b = bf16_rne(r);
            r -= bf16_back(b);
        }
        frag[jj] = (short)b;
    }
    wsfrag[blk * 64 + l] = frag;
}

__global__ __launch_bounds__(256, 3) void snn_fused_kernel(
    const float* __restrict__ x,        // [4096, 1, 28, 28]
    const float* __restrict__ conv_w,   // [8, 1, 3, 3]
    const s16x8* __restrict__ wsfrag,   // [SPLITS*KS*64] B fragments
    float* __restrict__ out)            // [4096, 10]
{
    const int b    = blockIdx.x;
    const int tid  = threadIdx.x;
    const int lane = tid & 63;
    const int wid  = tid >> 6;          // 0..3

    // counts matrix in A-fragment order:
    // short index(u,t) = (u>>5)*544 + ((u&31)>>3)*136 + t*8 + (u&7)
    __shared__ unsigned short sA[KS * 544];   // 46.75 KB
    __shared__ float scC[4 * 256];            // per-wave partial C [w][t*16+o]
    __shared__ float scw[72];                 // conv weights
    __shared__ float scur2[160];              // [t][o]

    if (tid < 72) scw[tid] = conv_w[tid];

    // ---- per-thread unit geometry ----
    int xbase[NU], kbase[NU], sbase[NU];
    #pragma unroll
    for (int i = 0; i < NU; ++i) {
        const int u      = tid + 256 * i;
        const bool valid = (u < 1352);
        const int uu  = valid ? u : 0;
        const int k   = uu / 169;           // channel
        const int rem = uu - k * 169;
        const int pr  = rem / 13;           // pool row
        const int pc  = rem - pr * 13;      // pool col
        xbase[i] = 56 * pr + 2 * pc;
        kbase[i] = 9 * k;
        const int uo = u & 31;
        sbase[i] = (u >> 5) * 544 + (uo >> 3) * 136 + (uo & 7);
    }
    __syncthreads();                        // scw ready

    // ---- conv straight from global (3KB image, L2/L3-resident) ----
    const float* xb = x + (size_t)b * 784;
    v2f cur2[NU][2];   // conv out [unit][{cells01, cells23}]
    v2f mem2[NU][2];   // LIF-1 membranes
    #pragma unroll
    for (int i = 0; i < NU; ++i) {
        float cw[9];
        #pragma unroll
        for (int qq = 0; qq < 9; ++qq) cw[qq] = scw[kbase[i] + qq];

        float xr[4][4];
        #pragma unroll
        for (int r = 0; r < 4; ++r) {
            const float2* rp = reinterpret_cast<const float2*>(xb + xbase[i] + 28 * r);
            const float2 a = rp[0], c2 = rp[1];
            xr[r][0] = a.x; xr[r][1] = a.y; xr[r][2] = c2.x; xr[r][3] = c2.y;
        }

        const bool valid = (tid + 256 * i) < 1352;
        float cell[2][2];
        #pragma unroll
        for (int dr = 0; dr < 2; ++dr)
            #pragma unroll
            for (int dc = 0; dc < 2; ++dc) {
                float acc = 0.0f;
                #pragma unroll
                for (int ki = 0; ki < 3; ++ki)
                    #pragma unroll
                    for (int kj = 0; kj < 3; ++kj)
                        acc += xr[dr + ki][dc + kj] * cw[ki * 3 + kj];
                cell[dr][dc] = valid ? acc : 0.0f;
            }
        cur2[i][0] = (v2f){cell[0][0], cell[0][1]};
        cur2[i][1] = (v2f){cell[1][0], cell[1][1]};
        mem2[i][0] = (v2f){0.0f, 0.0f};
        mem2[i][1] = (v2f){0.0f, 0.0f};
    }

    const v2f half2 = (v2f){0.5f, 0.5f};

    // ---- phase 1: 16 timesteps of pure LIF; counts -> sA as bf16 ----
    #pragma unroll
    for (int t = 0; t < 16; ++t) {
        #pragma unroll
        for (int i = 0; i < NU; ++i) {
            v2f m01 = VFMA(half2, mem2[i][0], cur2[i][0]);
            v2f m23 = VFMA(half2, mem2[i][1], cur2[i][1]);
            v2f sp01, sp23;
            sp01.x = m01.x > 1.0f ? 1.0f : 0.0f;    // spike iff m > THR
            sp01.y = m01.y > 1.0f ? 1.0f : 0.0f;
            sp23.x = m23.x > 1.0f ? 1.0f : 0.0f;
            sp23.y = m23.y > 1.0f ? 1.0f : 0.0f;
            mem2[i][0] = m01 - sp01;                // subtract-reset (bit-identical)
            mem2[i][1] = m23 - sp23;
            v2f s = sp01 + sp23;
            const float c = s.x + s.y;              // 0..4 exact
            const unsigned short cb = (unsigned short)(__float_as_uint(c) >> 16);
            if (i < 5 || tid < 96)                  // u < 1376 only
                sA[sbase[i] + t * 8] = cb;
        }
    }
    __syncthreads();                                // counts complete

    // ---- phase 2: wave p computes split p of the [16x1376]x[1376x16] ----
    {
        const int p = wid;                          // split index == wave id
        f32x4 acc = (f32x4){0.f, 0.f, 0.f, 0.f};
        const int arow = (lane >> 4) * 136 + (lane & 15) * 8;
        #pragma unroll 2
        for (int ks = 0; ks < KS; ++ks) {
            const s16x8 a  = *reinterpret_cast<const s16x8*>(&sA[ks * 544 + arow]);
            const s16x8 bw = wsfrag[(p * KS + ks) * 64 + lane];
            acc = __builtin_amdgcn_mfma_f32_16x16x32_bf16(a, bw, acc, 0, 0, 0);
        }
        // store partial C: row t = (l>>4)*4 + r, col o = l&15 (verified layout)
        const int o = lane & 15;
        #pragma unroll
        for (int r = 0; r < 4; ++r) {
            const int t = (lane >> 4) * 4 + r;
            scC[wid * 256 + t * 16 + o] = acc[r];
        }
    }
    __syncthreads();                                // partials ready

    // ---- combine splits (same pairwise order as r13) + LIF-2 scan ----
    if (tid < 160) {
        const int t = tid / 10;
        const int o = tid - t * 10;
        const int idx = t * 16 + o;
        scur2[tid] = (scC[idx] + scC[256 + idx]) + (scC[512 + idx] + scC[768 + idx]);
    }
    __syncthreads();                                // scur2 ready

    if (tid < 10) {
        float m2 = 0.0f, cnt = 0.0f;
        #pragma unroll
        for (int t = 0; t < 16; ++t) {
            m2 = __builtin_fmaf(0.5f, m2, scur2[t * 10 + tid]);
            float ms = m2 - 1.0f;
            bool  sp = ms > 0.0f;
            m2  = sp ? ms : m2;
            cnt += sp ? 1.0f : 0.0f;
        }
        out[(size_t)b * 10 + tid] = cnt;
    }
}

extern "C" void kernel_launch(void* const* d_in, const int* in_sizes, int n_in,
                              void* d_out, int out_size, void* d_ws, size_t ws_size,
                              hipStream_t stream) {
    const float* x      = (const float*)d_in[0];  // 4096*784
    const float* conv_w = (const float*)d_in[1];  // 72
    const float* fc_w   = (const float*)d_in[2];  // 13520
    float* out          = (float*)d_out;          // 40960
    s16x8* wsfrag       = (s16x8*)d_ws;           // needs 176128 B

    build_bfrag_kernel<<<SPLITS * KS, 64, 0, stream>>>(fc_w, wsfrag);

    const int B = in_sizes[0] / 784;              // 4096
    snn_fused_kernel<<<B, 256, 0, stream>>>(x, conv_w, wsfrag, out);
}